// Round 1
// baseline (1678.618 us; speedup 1.0000x reference)
//
#include <hip/hip_runtime.h>

#define B_ 8
#define N_ 1024
#define C_ 768
#define H_ 12
#define D_ 64
#define SCALE_ 0.125f

// ---------------------------------------------------------------------------
// K1: qkv = x[8192,768] @ w_qkv[2304,768]^T, scattered to q/k/v as [B,H,N,D].
// 64x64 block tile, TK=32, 4x4 micro-tile, k-major LDS tiles (stride 68 keeps
// float4 alignment, 2-way-max bank aliasing on b128 reads = free).
// ---------------------------------------------------------------------------
__global__ __launch_bounds__(256) void qkv_gemm(const float* __restrict__ X,
                                                const float* __restrict__ W,
                                                float* __restrict__ q,
                                                float* __restrict__ k,
                                                float* __restrict__ v) {
    __shared__ float As[32][68];
    __shared__ float Bs[32][68];
    const int t = threadIdx.x;
    const int tx = t & 15, ty = t >> 4;
    const int m0 = blockIdx.x * 64;
    const int n0 = blockIdx.y * 64;
    const int lr = t >> 3, lc4 = t & 7;   // 64 rows x 8 float4-cols per tile
    float acc[4][4] = {};
    for (int k0 = 0; k0 < C_; k0 += 32) {
        #pragma unroll
        for (int i = 0; i < 2; ++i) {
            const int r = lr + i * 32;
            const float4 a = *(const float4*)&X[(size_t)(m0 + r) * C_ + k0 + lc4 * 4];
            const float4 b = *(const float4*)&W[(size_t)(n0 + r) * C_ + k0 + lc4 * 4];
            As[lc4 * 4 + 0][r] = a.x; As[lc4 * 4 + 1][r] = a.y;
            As[lc4 * 4 + 2][r] = a.z; As[lc4 * 4 + 3][r] = a.w;
            Bs[lc4 * 4 + 0][r] = b.x; Bs[lc4 * 4 + 1][r] = b.y;
            Bs[lc4 * 4 + 2][r] = b.z; Bs[lc4 * 4 + 3][r] = b.w;
        }
        __syncthreads();
        #pragma unroll
        for (int kk = 0; kk < 32; ++kk) {
            const float4 a4 = *(const float4*)&As[kk][ty * 4];
            const float4 b4 = *(const float4*)&Bs[kk][tx * 4];
            const float a[4] = {a4.x, a4.y, a4.z, a4.w};
            const float b[4] = {b4.x, b4.y, b4.z, b4.w};
            #pragma unroll
            for (int i = 0; i < 4; ++i)
                #pragma unroll
                for (int j = 0; j < 4; ++j) acc[i][j] += a[i] * b[j];
        }
        __syncthreads();
    }
    // scatter: e = n0 + tx*4+j ; which = e/768, h = (e%768)/64, d = tx*4+j
    const int which = n0 / C_;
    const int h = (n0 % C_) / D_;
    float* dst = which == 0 ? q : (which == 1 ? k : v);
    #pragma unroll
    for (int i = 0; i < 4; ++i) {
        const int m = m0 + ty * 4 + i;
        const int b = m >> 10, n = m & 1023;
        *(float4*)&dst[(size_t)((b * H_ + h) * N_ + n) * D_ + tx * 4] =
            make_float4(acc[i][0], acc[i][1], acc[i][2], acc[i][3]);
    }
}

// ---------------------------------------------------------------------------
// K2: fused scores + softmax. Block = 16 q-rows x full 1024 cols of one head.
// Thread (r = t>>4, c0 = t&15) owns cols c0+16*i, i=0..63 (s[64] in VGPRs).
// Row softmax via width-16 shfl_xor (the 16 owner threads are consecutive).
// ---------------------------------------------------------------------------
__global__ __launch_bounds__(256) void attn_softmax(const float* __restrict__ q,
                                                    const float* __restrict__ k,
                                                    float* __restrict__ attn) {
    __shared__ float qs[16][68];
    __shared__ float ks[64][68];
    const int t = threadIdx.x;
    const int c0 = t & 15, r = t >> 4;
    const int mt = blockIdx.x;   // 0..63 (16-row tiles)
    const int bh = blockIdx.y;   // 0..95
    const size_t base = (size_t)bh * N_ * D_;
    {
        const int row = t >> 4, c4 = t & 15;
        *(float4*)&qs[row][c4 * 4] =
            *(const float4*)&q[base + (size_t)(mt * 16 + row) * D_ + c4 * 4];
    }
    float s[64];
    #pragma unroll
    for (int i = 0; i < 64; ++i) s[i] = 0.f;
    for (int kt = 0; kt < 16; ++kt) {
        __syncthreads();
        #pragma unroll
        for (int i = 0; i < 4; ++i) {
            const int idx = i * 256 + t;
            const int row = idx >> 4, c4 = idx & 15;
            *(float4*)&ks[row][c4 * 4] =
                *(const float4*)&k[base + (size_t)(kt * 64 + row) * D_ + c4 * 4];
        }
        __syncthreads();
        #pragma unroll
        for (int d4 = 0; d4 < 16; ++d4) {
            const float4 q4 = *(const float4*)&qs[r][d4 * 4];
            #pragma unroll
            for (int u = 0; u < 4; ++u) {
                const float4 k4 = *(const float4*)&ks[c0 + 16 * u][d4 * 4];
                s[kt * 4 + u] += q4.x * k4.x + q4.y * k4.y + q4.z * k4.z + q4.w * k4.w;
            }
        }
    }
    float m = -1e30f;
    #pragma unroll
    for (int i = 0; i < 64; ++i) m = fmaxf(m, s[i] * SCALE_);
    #pragma unroll
    for (int mask = 8; mask; mask >>= 1) m = fmaxf(m, __shfl_xor(m, mask, 16));
    float sum = 0.f;
    #pragma unroll
    for (int i = 0; i < 64; ++i) { s[i] = __expf(s[i] * SCALE_ - m); sum += s[i]; }
    #pragma unroll
    for (int mask = 8; mask; mask >>= 1) sum += __shfl_xor(sum, mask, 16);
    const float inv = 1.0f / sum;
    const size_t rowbase = ((size_t)bh * N_ + mt * 16 + r) * N_;
    #pragma unroll
    for (int i = 0; i < 64; ++i) attn[rowbase + c0 + 16 * i] = s[i] * inv;
}

// ---------------------------------------------------------------------------
// K3: oa[b,n,h*64+d] = attn[b,h,n,:] @ v[b,h,:,d]. 64x64 M-K tiles, N=D=64.
// ---------------------------------------------------------------------------
__global__ __launch_bounds__(256) void attn_v(const float* __restrict__ attn,
                                              const float* __restrict__ v,
                                              float* __restrict__ oa) {
    __shared__ float As[64][68];   // [k][m]
    __shared__ float Vs[64][68];   // [k][d]
    const int t = threadIdx.x;
    const int tx = t & 15, ty = t >> 4;
    const int mt = blockIdx.x;   // 0..15
    const int bh = blockIdx.y;   // 0..95
    const int b = bh / H_, h = bh % H_;
    float acc[4][4] = {};
    for (int k0 = 0; k0 < N_; k0 += 64) {
        #pragma unroll
        for (int i = 0; i < 4; ++i) {
            const int idx = i * 256 + t;
            const int r = idx >> 4, c4 = idx & 15;
            const float4 a =
                *(const float4*)&attn[((size_t)bh * N_ + mt * 64 + r) * N_ + k0 + c4 * 4];
            As[c4 * 4 + 0][r] = a.x; As[c4 * 4 + 1][r] = a.y;
            As[c4 * 4 + 2][r] = a.z; As[c4 * 4 + 3][r] = a.w;
            *(float4*)&Vs[r][c4 * 4] =
                *(const float4*)&v[((size_t)bh * N_ + k0 + r) * D_ + c4 * 4];
        }
        __syncthreads();
        #pragma unroll
        for (int kk = 0; kk < 64; ++kk) {
            const float4 a4 = *(const float4*)&As[kk][ty * 4];
            const float4 b4 = *(const float4*)&Vs[kk][tx * 4];
            const float a[4] = {a4.x, a4.y, a4.z, a4.w};
            const float bb[4] = {b4.x, b4.y, b4.z, b4.w};
            #pragma unroll
            for (int i = 0; i < 4; ++i)
                #pragma unroll
                for (int j = 0; j < 4; ++j) acc[i][j] += a[i] * bb[j];
        }
        __syncthreads();
    }
    #pragma unroll
    for (int i = 0; i < 4; ++i) {
        const int n = mt * 64 + ty * 4 + i;
        *(float4*)&oa[((size_t)b * N_ + n) * C_ + h * D_ + tx * 4] =
            make_float4(acc[i][0], acc[i][1], acc[i][2], acc[i][3]);
    }
}

// ---------------------------------------------------------------------------
// K4: out = oa[8192,768] @ w_proj[768,768]^T + b_proj. Same core as K1.
// ---------------------------------------------------------------------------
__global__ __launch_bounds__(256) void proj_gemm(const float* __restrict__ X,
                                                 const float* __restrict__ W,
                                                 const float* __restrict__ Bias,
                                                 float* __restrict__ out) {
    __shared__ float As[32][68];
    __shared__ float Bs[32][68];
    const int t = threadIdx.x;
    const int tx = t & 15, ty = t >> 4;
    const int m0 = blockIdx.x * 64;
    const int n0 = blockIdx.y * 64;
    const int lr = t >> 3, lc4 = t & 7;
    float acc[4][4] = {};
    for (int k0 = 0; k0 < C_; k0 += 32) {
        #pragma unroll
        for (int i = 0; i < 2; ++i) {
            const int r = lr + i * 32;
            const float4 a = *(const float4*)&X[(size_t)(m0 + r) * C_ + k0 + lc4 * 4];
            const float4 b = *(const float4*)&W[(size_t)(n0 + r) * C_ + k0 + lc4 * 4];
            As[lc4 * 4 + 0][r] = a.x; As[lc4 * 4 + 1][r] = a.y;
            As[lc4 * 4 + 2][r] = a.z; As[lc4 * 4 + 3][r] = a.w;
            Bs[lc4 * 4 + 0][r] = b.x; Bs[lc4 * 4 + 1][r] = b.y;
            Bs[lc4 * 4 + 2][r] = b.z; Bs[lc4 * 4 + 3][r] = b.w;
        }
        __syncthreads();
        #pragma unroll
        for (int kk = 0; kk < 32; ++kk) {
            const float4 a4 = *(const float4*)&As[kk][ty * 4];
            const float4 b4 = *(const float4*)&Bs[kk][tx * 4];
            const float a[4] = {a4.x, a4.y, a4.z, a4.w};
            const float b[4] = {b4.x, b4.y, b4.z, b4.w};
            #pragma unroll
            for (int i = 0; i < 4; ++i)
                #pragma unroll
                for (int j = 0; j < 4; ++j) acc[i][j] += a[i] * b[j];
        }
        __syncthreads();
    }
    const float4 bias = *(const float4*)&Bias[n0 + tx * 4];
    #pragma unroll
    for (int i = 0; i < 4; ++i) {
        const int m = m0 + ty * 4 + i;
        *(float4*)&out[(size_t)m * C_ + n0 + tx * 4] =
            make_float4(acc[i][0] + bias.x, acc[i][1] + bias.y,
                        acc[i][2] + bias.z, acc[i][3] + bias.w);
    }
}

extern "C" void kernel_launch(void* const* d_in, const int* in_sizes, int n_in,
                              void* d_out, int out_size, void* d_ws, size_t ws_size,
                              hipStream_t stream) {
    const float* x      = (const float*)d_in[0];
    const float* w_qkv  = (const float*)d_in[1];
    const float* w_proj = (const float*)d_in[2];
    const float* b_proj = (const float*)d_in[3];

    float* out  = (float*)d_out;                       // [8,1024,768]
    float* attn = out + (size_t)B_ * N_ * C_;          // [8,12,1024,1024]

    const size_t SZ = (size_t)B_ * H_ * N_ * D_;       // 6,291,456 floats
    float* q  = (float*)d_ws;
    float* k  = q + SZ;
    float* v  = k + SZ;
    float* oa = v + SZ;                                 // pre-proj [8,1024,768]

    qkv_gemm    <<<dim3(128, 36), 256, 0, stream>>>(x, w_qkv, q, k, v);
    attn_softmax<<<dim3(64, 96), 256, 0, stream>>>(q, k, attn);
    attn_v      <<<dim3(16, 96), 256, 0, stream>>>(attn, v, oa);
    proj_gemm   <<<dim3(128, 12), 256, 0, stream>>>(oa, w_proj, b_proj, out);
}

// Round 2
// 674.893 us; speedup vs baseline: 2.4872x; 2.4872x over previous
//
#include <hip/hip_runtime.h>

#define B_ 8
#define N_ 1024
#define C_ 768
#define H_ 12
#define D_ 64
#define SCALE_ 0.125f

typedef _Float16 v8h __attribute__((ext_vector_type(8)));
typedef float v4f __attribute__((ext_vector_type(4)));

__device__ __forceinline__ void gload_lds16(const void* g, void* l) {
    __builtin_amdgcn_global_load_lds((const __attribute__((address_space(1))) void*)g,
                                     (__attribute__((address_space(3))) void*)l, 16, 0, 0);
}

// ---------------------------------------------------------------------------
// cast fp32 -> fp16, 8 elems/thread
// ---------------------------------------------------------------------------
__global__ __launch_bounds__(256) void cast_f2h(const float* __restrict__ src,
                                                _Float16* __restrict__ dst, int n8) {
    const int i = blockIdx.x * 256 + threadIdx.x;
    if (i < n8) {
        const v4f a = *(const v4f*)&src[(size_t)i * 8];
        const v4f b = *(const v4f*)&src[(size_t)i * 8 + 4];
        v8h o;
        o[0] = (_Float16)a[0]; o[1] = (_Float16)a[1]; o[2] = (_Float16)a[2]; o[3] = (_Float16)a[3];
        o[4] = (_Float16)b[0]; o[5] = (_Float16)b[1]; o[6] = (_Float16)b[2]; o[7] = (_Float16)b[3];
        *(v8h*)&dst[(size_t)i * 8] = o;
    }
}

// ---------------------------------------------------------------------------
// K1: qkv = xh[8192,768] @ wqh[2304,768]^T (both fp16, K-major) via MFMA.
// 128x128 tile, BK=32, 4 waves 2x2, global_load_lds(16B) staging.
// Epilogue scatters to q,k [B,H,N,D] and v TRANSPOSED [B,H,D,N], fp16.
// ---------------------------------------------------------------------------
__global__ __launch_bounds__(256) void gemm_qkv(const _Float16* __restrict__ X,
                                                const _Float16* __restrict__ W,
                                                _Float16* __restrict__ qh,
                                                _Float16* __restrict__ kh,
                                                _Float16* __restrict__ vth) {
    __shared__ _Float16 As[128 * 32];
    __shared__ _Float16 Bs[128 * 32];
    const int t = threadIdx.x;
    const int w = t >> 6, l = t & 63;
    const int q4 = l >> 4, c0 = l & 15;
    const int wm = w & 1, wn = w >> 1;
    const int m0 = blockIdx.x * 128, n0 = blockIdx.y * 128;
    const int sc8 = (t & 3) * 8;
    v4f acc[4][4] = {};
    for (int k0 = 0; k0 < C_; k0 += 32) {
        #pragma unroll
        for (int i = 0; i < 2; ++i) {
            const int row = i * 64 + (t >> 2);
            gload_lds16(&X[(size_t)(m0 + row) * C_ + k0 + sc8], &As[(i * 256 + t) * 8]);
            gload_lds16(&W[(size_t)(n0 + row) * C_ + k0 + sc8], &Bs[(i * 256 + t) * 8]);
        }
        __syncthreads();
        v8h a[4], b[4];
        #pragma unroll
        for (int mi = 0; mi < 4; ++mi)
            a[mi] = *(const v8h*)&As[(wm * 64 + mi * 16 + c0) * 32 + q4 * 8];
        #pragma unroll
        for (int ni = 0; ni < 4; ++ni)
            b[ni] = *(const v8h*)&Bs[(wn * 64 + ni * 16 + c0) * 32 + q4 * 8];
        #pragma unroll
        for (int mi = 0; mi < 4; ++mi)
            #pragma unroll
            for (int ni = 0; ni < 4; ++ni)
                acc[mi][ni] = __builtin_amdgcn_mfma_f32_16x16x32_f16(a[mi], b[ni], acc[mi][ni], 0, 0, 0);
        __syncthreads();
    }
    const int which = n0 / C_;       // block fully inside one of q/k/v
    const int nbase = n0 % C_;
    #pragma unroll
    for (int ni = 0; ni < 4; ++ni) {
        const int n = nbase + wn * 64 + ni * 16 + c0;
        const int h = n >> 6, d = n & 63;
        #pragma unroll
        for (int mi = 0; mi < 4; ++mi) {
            #pragma unroll
            for (int r = 0; r < 4; ++r) {
                const int m = m0 + wm * 64 + mi * 16 + q4 * 4 + r;
                const int b = m >> 10, nn = m & 1023;
                const _Float16 val = (_Float16)acc[mi][ni][r];
                if (which == 0)
                    qh[((size_t)(b * H_ + h) * N_ + nn) * D_ + d] = val;
                else if (which == 1)
                    kh[((size_t)(b * H_ + h) * N_ + nn) * D_ + d] = val;
                else
                    vth[((size_t)(b * H_ + h) * D_ + d) * N_ + nn] = val;
            }
        }
    }
}

// ---------------------------------------------------------------------------
// K2: fused attention. Block = 16 q-rows x one (b,h). Grid (64, 96).
// QK^T via MFMA over 128-row K chunks; fp32 softmax (shfl16 + LDS x-wave);
// then 8 slabs of 128 cols: dump normalized P to LDS -> coalesced fp32 attn
// stores -> P as A-frags (cvt fp16) x Vt slab (B-frags) -> O accumulator.
// ---------------------------------------------------------------------------
__global__ __launch_bounds__(256) void attn_fused(const _Float16* __restrict__ qh,
                                                  const _Float16* __restrict__ kh,
                                                  const _Float16* __restrict__ vth,
                                                  float* __restrict__ attn,
                                                  _Float16* __restrict__ oah) {
    __shared__ _Float16 Qs[2 * 16 * 32];    // [piece][row][32]
    __shared__ _Float16 Ks[2 * 128 * 32];   // [piece][row][32]
    __shared__ _Float16 Vt[4 * 64 * 32];    // [piece][d][32]
    __shared__ float Ps[16 * 132];          // P slab, stride 132
    __shared__ float redm[64], reds[64];    // [wave][row]
    const int t = threadIdx.x;
    const int w = t >> 6, l = t & 63;
    const int q4 = l >> 4, c0 = l & 15;
    const int mt = blockIdx.x, bh = blockIdx.y;
    const size_t qkbase = (size_t)bh * N_ * D_;
    const size_t vtbase = (size_t)bh * D_ * N_;

    // stage Qs (waves 0,1) and Ks chunk 0
    if (w < 2)
        gload_lds16(&qh[qkbase + (size_t)(mt * 16 + (l >> 2)) * D_ + w * 32 + (l & 3) * 8],
                    &Qs[t * 8]);
    #pragma unroll
    for (int i = 0; i < 4; ++i) {
        const int idx = i * 256 + t;
        const int p = idx >> 9, row = (idx & 511) >> 2, c8 = (idx & 3) * 8;
        gload_lds16(&kh[qkbase + (size_t)row * D_ + p * 32 + c8], &Ks[idx * 8]);
    }
    __syncthreads();
    v8h a0 = *(const v8h*)&Qs[c0 * 32 + q4 * 8];
    v8h a1 = *(const v8h*)&Qs[512 + c0 * 32 + q4 * 8];

    v4f S[16];
    #pragma unroll
    for (int i = 0; i < 16; ++i) S[i] = (v4f){0.f, 0.f, 0.f, 0.f};

    for (int c = 0; c < 8; ++c) {
        #pragma unroll
        for (int h2 = 0; h2 < 2; ++h2) {
            const int roff = (h2 * 64 + w * 16 + c0) * 32 + q4 * 8;
            const v8h b0 = *(const v8h*)&Ks[roff];
            const v8h b1 = *(const v8h*)&Ks[4096 + roff];
            v4f acc = __builtin_amdgcn_mfma_f32_16x16x32_f16(a0, b0, S[c * 2 + h2], 0, 0, 0);
            S[c * 2 + h2] = __builtin_amdgcn_mfma_f32_16x16x32_f16(a1, b1, acc, 0, 0, 0);
        }
        if (c < 7) {
            __syncthreads();
            #pragma unroll
            for (int i = 0; i < 4; ++i) {
                const int idx = i * 256 + t;
                const int p = idx >> 9, row = (idx & 511) >> 2, c8 = (idx & 3) * 8;
                gload_lds16(&kh[qkbase + (size_t)((c + 1) * 128 + row) * D_ + p * 32 + c8],
                            &Ks[idx * 8]);
            }
            __syncthreads();
        }
    }

    // ---- softmax (fp32) ----
    float mrow[4] = {-1e30f, -1e30f, -1e30f, -1e30f};
    #pragma unroll
    for (int kt = 0; kt < 16; ++kt)
        #pragma unroll
        for (int r = 0; r < 4; ++r) mrow[r] = fmaxf(mrow[r], S[kt][r]);
    #pragma unroll
    for (int r = 0; r < 4; ++r) {
        #pragma unroll
        for (int mask = 8; mask; mask >>= 1)
            mrow[r] = fmaxf(mrow[r], __shfl_xor(mrow[r], mask, 16));
    }
    if (c0 == 0) {
        #pragma unroll
        for (int r = 0; r < 4; ++r) redm[w * 16 + q4 * 4 + r] = mrow[r];
    }
    __syncthreads();
    #pragma unroll
    for (int r = 0; r < 4; ++r) {
        float mm = redm[q4 * 4 + r];
        mm = fmaxf(mm, redm[16 + q4 * 4 + r]);
        mm = fmaxf(mm, redm[32 + q4 * 4 + r]);
        mm = fmaxf(mm, redm[48 + q4 * 4 + r]);
        mrow[r] = mm;
    }
    float srow[4] = {0.f, 0.f, 0.f, 0.f};
    #pragma unroll
    for (int kt = 0; kt < 16; ++kt)
        #pragma unroll
        for (int r = 0; r < 4; ++r) {
            const float e = __expf((S[kt][r] - mrow[r]) * SCALE_);
            S[kt][r] = e;
            srow[r] += e;
        }
    #pragma unroll
    for (int r = 0; r < 4; ++r) {
        #pragma unroll
        for (int mask = 8; mask; mask >>= 1) srow[r] += __shfl_xor(srow[r], mask, 16);
    }
    if (c0 == 0) {
        #pragma unroll
        for (int r = 0; r < 4; ++r) reds[w * 16 + q4 * 4 + r] = srow[r];
    }
    __syncthreads();
    float inv[4];
    #pragma unroll
    for (int r = 0; r < 4; ++r)
        inv[r] = 1.0f / (reds[q4 * 4 + r] + reds[16 + q4 * 4 + r] +
                         reds[32 + q4 * 4 + r] + reds[48 + q4 * 4 + r]);

    // ---- slabs: attn store + O accumulation ----
    v4f O = {0.f, 0.f, 0.f, 0.f};
    for (int s = 0; s < 8; ++s) {
        #pragma unroll
        for (int kt2 = 0; kt2 < 2; ++kt2)
            #pragma unroll
            for (int r = 0; r < 4; ++r)
                Ps[(q4 * 4 + r) * 132 + kt2 * 64 + w * 16 + c0] = S[s * 2 + kt2][r] * inv[r];
        #pragma unroll
        for (int i = 0; i < 4; ++i)
            gload_lds16(&vth[vtbase + (size_t)(t >> 2) * N_ + s * 128 + i * 32 + (t & 3) * 8],
                        &Vt[(i * 256 + t) * 8]);
        __syncthreads();
        #pragma unroll
        for (int i = 0; i < 2; ++i) {
            const int cidx = i * 256 + t;
            const int row = cidx >> 5, col = (cidx & 31) * 4;
            *(v4f*)&attn[((size_t)bh * N_ + mt * 16 + row) * N_ + s * 128 + col] =
                *(const v4f*)&Ps[row * 132 + col];
        }
        #pragma unroll
        for (int kk = 0; kk < 4; ++kk) {
            const float* pp = &Ps[c0 * 132 + kk * 32 + q4 * 8];
            const v4f p0 = *(const v4f*)pp;
            const v4f p1 = *(const v4f*)(pp + 4);
            v8h af;
            af[0] = (_Float16)p0[0]; af[1] = (_Float16)p0[1];
            af[2] = (_Float16)p0[2]; af[3] = (_Float16)p0[3];
            af[4] = (_Float16)p1[0]; af[5] = (_Float16)p1[1];
            af[6] = (_Float16)p1[2]; af[7] = (_Float16)p1[3];
            const v8h bf = *(const v8h*)&Vt[kk * 2048 + (w * 16 + c0) * 32 + q4 * 8];
            O = __builtin_amdgcn_mfma_f32_16x16x32_f16(af, bf, O, 0, 0, 0);
        }
        __syncthreads();
    }
    const int b = bh / H_, h = bh % H_;
    #pragma unroll
    for (int r = 0; r < 4; ++r)
        oah[((size_t)b * N_ + mt * 16 + q4 * 4 + r) * C_ + h * D_ + w * 16 + c0] = (_Float16)O[r];
}

// ---------------------------------------------------------------------------
// K4: out = oah[8192,768] @ wph[768,768]^T + bias, fp32 out. Same as K1 core.
// ---------------------------------------------------------------------------
__global__ __launch_bounds__(256) void gemm_proj(const _Float16* __restrict__ X,
                                                 const _Float16* __restrict__ W,
                                                 const float* __restrict__ Bias,
                                                 float* __restrict__ out) {
    __shared__ _Float16 As[128 * 32];
    __shared__ _Float16 Bs[128 * 32];
    const int t = threadIdx.x;
    const int w = t >> 6, l = t & 63;
    const int q4 = l >> 4, c0 = l & 15;
    const int wm = w & 1, wn = w >> 1;
    const int m0 = blockIdx.x * 128, n0 = blockIdx.y * 128;
    const int sc8 = (t & 3) * 8;
    v4f acc[4][4] = {};
    for (int k0 = 0; k0 < C_; k0 += 32) {
        #pragma unroll
        for (int i = 0; i < 2; ++i) {
            const int row = i * 64 + (t >> 2);
            gload_lds16(&X[(size_t)(m0 + row) * C_ + k0 + sc8], &As[(i * 256 + t) * 8]);
            gload_lds16(&W[(size_t)(n0 + row) * C_ + k0 + sc8], &Bs[(i * 256 + t) * 8]);
        }
        __syncthreads();
        v8h a[4], b[4];
        #pragma unroll
        for (int mi = 0; mi < 4; ++mi)
            a[mi] = *(const v8h*)&As[(wm * 64 + mi * 16 + c0) * 32 + q4 * 8];
        #pragma unroll
        for (int ni = 0; ni < 4; ++ni)
            b[ni] = *(const v8h*)&Bs[(wn * 64 + ni * 16 + c0) * 32 + q4 * 8];
        #pragma unroll
        for (int mi = 0; mi < 4; ++mi)
            #pragma unroll
            for (int ni = 0; ni < 4; ++ni)
                acc[mi][ni] = __builtin_amdgcn_mfma_f32_16x16x32_f16(a[mi], b[ni], acc[mi][ni], 0, 0, 0);
        __syncthreads();
    }
    #pragma unroll
    for (int ni = 0; ni < 4; ++ni) {
        const int n = n0 + wn * 64 + ni * 16 + c0;
        const float bias = Bias[n];
        #pragma unroll
        for (int mi = 0; mi < 4; ++mi) {
            #pragma unroll
            for (int r = 0; r < 4; ++r) {
                const int m = m0 + wm * 64 + mi * 16 + q4 * 4 + r;
                out[(size_t)m * C_ + n] = acc[mi][ni][r] + bias;
            }
        }
    }
}

extern "C" void kernel_launch(void* const* d_in, const int* in_sizes, int n_in,
                              void* d_out, int out_size, void* d_ws, size_t ws_size,
                              hipStream_t stream) {
    const float* x      = (const float*)d_in[0];
    const float* w_qkv  = (const float*)d_in[1];
    const float* w_proj = (const float*)d_in[2];
    const float* b_proj = (const float*)d_in[3];

    float* out  = (float*)d_out;                 // [8,1024,768]
    float* attn = out + (size_t)B_ * N_ * C_;    // [8,12,1024,1024]

    const size_t NX  = (size_t)B_ * N_ * C_;     // 6,291,456
    const size_t NWQ = (size_t)3 * C_ * C_;      // 1,769,472
    const size_t NWP = (size_t)C_ * C_;          //   589,824
    _Float16* xh  = (_Float16*)d_ws;
    _Float16* wqh = xh + NX;
    _Float16* wph = wqh + NWQ;
    _Float16* qh  = wph + NWP;
    _Float16* kh  = qh + NX;
    _Float16* vth = kh + NX;
    _Float16* oah = vth + NX;

    cast_f2h<<<dim3((int)(NX / 8 / 256)), 256, 0, stream>>>(x, xh, (int)(NX / 8));
    cast_f2h<<<dim3((int)(NWQ / 8 / 256)), 256, 0, stream>>>(w_qkv, wqh, (int)(NWQ / 8));
    cast_f2h<<<dim3((int)(NWP / 8 / 256)), 256, 0, stream>>>(w_proj, wph, (int)(NWP / 8));

    gemm_qkv  <<<dim3(64, 18), 256, 0, stream>>>(xh, wqh, qh, kh, vth);
    attn_fused<<<dim3(64, 96), 256, 0, stream>>>(qh, kh, vth, attn, oah);
    gemm_proj <<<dim3(64, 6), 256, 0, stream>>>(oah, wph, b_proj, out);
}